// Round 1
// baseline (1556.892 us; speedup 1.0000x reference)
//
#include <hip/hip_runtime.h>
#include <hip/hip_bf16.h>
#include <cstdint>
#include <cstddef>

#define BB 64
#define MM 1024
#define NN 1024
#define MSPLIT 16
#define ROWS_PER_CHUNK 64   // MM / MSPLIT
#define SUBROWS 8
#define N_ITERS 50
#define ALPHA_INV (1.0f / 0.3f)
#define EPSV 1e-8f
#define A_VAL (1.0f / 1024.0f)
#define B_VAL (1.0f / 1024.0f)

__device__ __forceinline__ float bf16_to_f(unsigned short u) {
    union { unsigned int i; float f; } w; w.i = ((unsigned int)u) << 16; return w.f;
}
__device__ __forceinline__ unsigned short f_to_bf16(float f) {
    union { float f; unsigned int i; } w; w.f = f;
    unsigned int r = w.i + 0x7FFFu + ((w.i >> 16) & 1u);   // round-to-nearest-even
    return (unsigned short)(r >> 16);
}

// Kernel A: K = exp(-cost/alpha) -> bf16, plus column-sum partials (u0 = 1).
__global__ __launch_bounds__(256) void kinit(const float* __restrict__ cost,
                                             unsigned short* __restrict__ kbuf,
                                             float* __restrict__ partial) {
    const int blk = blockIdx.x;
    const int b = blk >> 4, chunk = blk & 15;
    const int t = threadIdx.x;
    const int n0 = t * 4;
    const size_t base = ((size_t)b << 20) + (size_t)(chunk * ROWS_PER_CHUNK) * NN;
    const float* cb = cost + base;
    unsigned short* kb = kbuf + base;
    float s0 = 0.f, s1 = 0.f, s2 = 0.f, s3 = 0.f;
    for (int r = 0; r < ROWS_PER_CHUNK; ++r) {
        const float4 c = *reinterpret_cast<const float4*>(cb + (size_t)r * NN + n0);
        float k0 = __expf(-c.x * ALPHA_INV);
        float k1 = __expf(-c.y * ALPHA_INV);
        float k2 = __expf(-c.z * ALPHA_INV);
        float k3 = __expf(-c.w * ALPHA_INV);
        s0 += k0; s1 += k1; s2 += k2; s3 += k3;
        ushort4 kv;
        kv.x = f_to_bf16(k0); kv.y = f_to_bf16(k1);
        kv.z = f_to_bf16(k2); kv.w = f_to_bf16(k3);
        *reinterpret_cast<ushort4*>(kb + (size_t)r * NN + n0) = kv;
    }
    float4 ps; ps.x = s0; ps.y = s1; ps.z = s2; ps.w = s3;
    *reinterpret_cast<float4*>(partial + (size_t)(b * MSPLIT + chunk) * NN + n0) = ps;
}

// Reduce 16 column-sum partials -> v = b / (s + eps)
__global__ __launch_bounds__(256) void reduce_v(const float* __restrict__ partial,
                                                float* __restrict__ v) {
    const int b = blockIdx.x;
    const int n0 = threadIdx.x * 4;
    const float* p = partial + (size_t)b * MSPLIT * NN + n0;
    float s0 = 0.f, s1 = 0.f, s2 = 0.f, s3 = 0.f;
#pragma unroll
    for (int c = 0; c < MSPLIT; ++c) {
        float4 q = *reinterpret_cast<const float4*>(p + (size_t)c * NN);
        s0 += q.x; s1 += q.y; s2 += q.z; s3 += q.w;
    }
    float4 out;
    out.x = B_VAL / (s0 + EPSV);
    out.y = B_VAL / (s1 + EPSV);
    out.z = B_VAL / (s2 + EPSV);
    out.w = B_VAL / (s3 + EPSV);
    *reinterpret_cast<float4*>(v + (size_t)b * NN + n0) = out;
}

// Fused iteration: u = a/(K v + eps) (row dots), then column-sum partials
// weighted by the fresh u (feeding next iteration's v). One K sweep per iter;
// the phase-2 re-read of the same 8-row sub-chunk is L1/L2-hot.
__global__ __launch_bounds__(256) void fused_iter(const unsigned short* __restrict__ kbuf,
                                                  const float* __restrict__ v,
                                                  float* __restrict__ u,
                                                  float* __restrict__ partial) {
    __shared__ float v_lds[NN];
    __shared__ float u_lds[ROWS_PER_CHUNK];
    const int blk = blockIdx.x;
    const int b = blk >> 4, chunk = blk & 15;
    const int t = threadIdx.x;
    const int wave = t >> 6, lane = t & 63;
    const int n0 = t * 4;

    *reinterpret_cast<float4*>(&v_lds[n0]) =
        *reinterpret_cast<const float4*>(v + (size_t)b * NN + n0);
    __syncthreads();

    const unsigned short* kb = kbuf + ((size_t)b << 20) + (size_t)(chunk * ROWS_PER_CHUNK) * NN;

    float acc0 = 0.f, acc1 = 0.f, acc2 = 0.f, acc3 = 0.f;

    for (int sc = 0; sc < ROWS_PER_CHUNK / SUBROWS; ++sc) {
        // Phase 1: row dots, 2 rows per wave
#pragma unroll
        for (int rr = 0; rr < 2; ++rr) {
            const int rloc = sc * SUBROWS + wave * 2 + rr;
            const unsigned short* row = kb + (size_t)rloc * NN;
            float dot = 0.f;
#pragma unroll
            for (int p = 0; p < 4; ++p) {
                const int col = p * 256 + lane * 4;
                ushort4 kk = *reinterpret_cast<const ushort4*>(row + col);
                float4 vv = *reinterpret_cast<const float4*>(&v_lds[col]);
                dot += bf16_to_f(kk.x) * vv.x + bf16_to_f(kk.y) * vv.y
                     + bf16_to_f(kk.z) * vv.z + bf16_to_f(kk.w) * vv.w;
            }
#pragma unroll
            for (int off = 32; off >= 1; off >>= 1)
                dot += __shfl_xor(dot, off, 64);
            if (lane == 0) u_lds[rloc] = A_VAL / (dot + EPSV);
        }
        __syncthreads();
        // Phase 2: column partial sums over the same (cache-hot) 8 rows
#pragma unroll
        for (int r = 0; r < SUBROWS; ++r) {
            const int rloc = sc * SUBROWS + r;
            const float uu = u_lds[rloc];
            ushort4 kk = *reinterpret_cast<const ushort4*>(kb + (size_t)rloc * NN + n0);
            acc0 += uu * bf16_to_f(kk.x);
            acc1 += uu * bf16_to_f(kk.y);
            acc2 += uu * bf16_to_f(kk.z);
            acc3 += uu * bf16_to_f(kk.w);
        }
        // no sync needed: next phase-1 writes disjoint u_lds entries
    }

    if (t < ROWS_PER_CHUNK)
        u[(size_t)b * MM + chunk * ROWS_PER_CHUNK + t] = u_lds[t];

    float4 ps; ps.x = acc0; ps.y = acc1; ps.z = acc2; ps.w = acc3;
    *reinterpret_cast<float4*>(partial + (size_t)(b * MSPLIT + chunk) * NN + n0) = ps;
}

// Final: P = u * exp(-cost/alpha) * v (fp32 K recomputed), per-block loss partials.
// Column mapping col = p*256 + t keeps dword stores coalesced despite the
// +1-float misalignment of the P region.
__global__ __launch_bounds__(256) void finalP(const float* __restrict__ cost,
                                              const float* __restrict__ u,
                                              const float* __restrict__ v,
                                              float* __restrict__ out,
                                              float* __restrict__ lossPart) {
    __shared__ float v_lds[NN];
    __shared__ float u_lds[ROWS_PER_CHUNK];
    __shared__ float wsum[4];
    const int blk = blockIdx.x;
    const int b = blk >> 4, chunk = blk & 15;
    const int t = threadIdx.x;

    *reinterpret_cast<float4*>(&v_lds[t * 4]) =
        *reinterpret_cast<const float4*>(v + (size_t)b * NN + t * 4);
    if (t < ROWS_PER_CHUNK)
        u_lds[t] = u[(size_t)b * MM + chunk * ROWS_PER_CHUNK + t];
    __syncthreads();

    const size_t base = ((size_t)b << 20) + (size_t)(chunk * ROWS_PER_CHUNK) * NN;
    const float* cb = cost + base;
    float* pb = out + 1 + base;
    float lacc = 0.f;
    for (int r = 0; r < ROWS_PER_CHUNK; ++r) {
        const float uu = u_lds[r];
#pragma unroll
        for (int p = 0; p < 4; ++p) {
            const int col = p * 256 + t;
            const float c = cb[(size_t)r * NN + col];
            const float pval = uu * __expf(-c * ALPHA_INV) * v_lds[col];
            pb[(size_t)r * NN + col] = pval;
            lacc += pval * c;
        }
    }
#pragma unroll
    for (int off = 32; off >= 1; off >>= 1)
        lacc += __shfl_xor(lacc, off, 64);
    if ((t & 63) == 0) wsum[t >> 6] = lacc;
    __syncthreads();
    if (t == 0) lossPart[blk] = wsum[0] + wsum[1] + wsum[2] + wsum[3];
}

__global__ __launch_bounds__(256) void lossReduce(const float* __restrict__ lossPart,
                                                  float* __restrict__ out) {
    __shared__ float wsum[4];
    const int t = threadIdx.x;
    float s = lossPart[t] + lossPart[t + 256] + lossPart[t + 512] + lossPart[t + 768];
#pragma unroll
    for (int off = 32; off >= 1; off >>= 1)
        s += __shfl_xor(s, off, 64);
    if ((t & 63) == 0) wsum[t >> 6] = s;
    __syncthreads();
    if (t == 0) out[0] = (wsum[0] + wsum[1] + wsum[2] + wsum[3]) * (1.0f / (float)BB);
}

extern "C" void kernel_launch(void* const* d_in, const int* in_sizes, int n_in,
                              void* d_out, int out_size, void* d_ws, size_t ws_size,
                              hipStream_t stream) {
    const float* cost = (const float*)d_in[0];
    float* out = (float*)d_out;

    // K (bf16, 128 MB) and column-sum partials (4 MB) live inside the P output
    // region — scratch until finalP overwrites it (finalP recomputes exp from
    // cost, so no read-after-overwrite hazard).
    unsigned short* kbuf = (unsigned short*)((char*)d_out + 1024);
    float* partial = (float*)((char*)d_out + 1024 + (size_t)BB * MM * NN * 2);

    // d_ws: u (256 KB) + v (256 KB) + lossPart (4 KB)
    float* u = (float*)d_ws;
    float* v = u + (size_t)BB * MM;
    float* lossPart = v + (size_t)BB * NN;

    kinit<<<BB * MSPLIT, 256, 0, stream>>>(cost, kbuf, partial);
    reduce_v<<<BB, 256, 0, stream>>>(partial, v);   // v_1

    for (int it = 0; it < N_ITERS; ++it) {
        fused_iter<<<BB * MSPLIT, 256, 0, stream>>>(kbuf, v, u, partial);
        if (it < N_ITERS - 1)
            reduce_v<<<BB, 256, 0, stream>>>(partial, v);
    }

    finalP<<<BB * MSPLIT, 256, 0, stream>>>(cost, u, v, out, lossPart);
    lossReduce<<<1, 256, 0, stream>>>(lossPart, out);
}

// Round 2
// 1066.677 us; speedup vs baseline: 1.4596x; 1.4596x over previous
//
#include <hip/hip_runtime.h>
#include <cstdint>
#include <cstddef>

#define BB 64
#define MM 1024
#define NN 1024
#define MSPLIT 16
#define RPC 64              // rows per chunk
#define N_ITERS 50
#define ALPHA_INV (1.0f / 0.3f)
#define EPSV 1e-8f
#define A_VAL (1.0f / 1024.0f)
#define B_VAL (1.0f / 1024.0f)

typedef float vf2 __attribute__((ext_vector_type(2)));

// XCD-affine mapping: all 16 chunk-blocks of a batch share bid%8 (same XCD under
// round-robin dispatch), so partial[b] is written and re-read on one XCD's L2.
// Bijection: bid = (b>>3) | ((b&7)<<3) | (chunk<<6).
__device__ __forceinline__ void decode_bid(int bid, int& b, int& chunk) {
    b = ((bid >> 3) & 7) * 8 + (bid & 7);
    chunk = bid >> 6;
}

__device__ __forceinline__ void unpack16(const uint4 kk, float* k) {
    vf2 p;
    p = __builtin_amdgcn_cvt_pk_f32_fp8(kk.x, false); k[0] = p.x; k[1] = p.y;
    p = __builtin_amdgcn_cvt_pk_f32_fp8(kk.x, true);  k[2] = p.x; k[3] = p.y;
    p = __builtin_amdgcn_cvt_pk_f32_fp8(kk.y, false); k[4] = p.x; k[5] = p.y;
    p = __builtin_amdgcn_cvt_pk_f32_fp8(kk.y, true);  k[6] = p.x; k[7] = p.y;
    p = __builtin_amdgcn_cvt_pk_f32_fp8(kk.z, false); k[8] = p.x; k[9] = p.y;
    p = __builtin_amdgcn_cvt_pk_f32_fp8(kk.z, true);  k[10] = p.x; k[11] = p.y;
    p = __builtin_amdgcn_cvt_pk_f32_fp8(kk.w, false); k[12] = p.x; k[13] = p.y;
    p = __builtin_amdgcn_cvt_pk_f32_fp8(kk.w, true);  k[14] = p.x; k[15] = p.y;
}

// K = exp(-cost/alpha) -> fp8 e4m3, plus column-sum partials (u0 = 1) computed
// from the DECODED fp8 values (consistent with the iteration's K').
__global__ __launch_bounds__(256) void kinit(const float* __restrict__ cost,
                                             unsigned char* __restrict__ kbuf,
                                             float* __restrict__ partial) {
    int b, chunk; decode_bid(blockIdx.x, b, chunk);
    const int t = threadIdx.x;
    const int n0 = t * 4;
    const size_t base = ((size_t)b << 20) + (size_t)(chunk * RPC) * NN;
    const float* cb = cost + base;
    unsigned char* kb = kbuf + base;
    float s0 = 0.f, s1 = 0.f, s2 = 0.f, s3 = 0.f;
    for (int r = 0; r < RPC; ++r) {
        const float4 c = *reinterpret_cast<const float4*>(cb + (size_t)r * NN + n0);
        float k0 = __expf(-c.x * ALPHA_INV);
        float k1 = __expf(-c.y * ALPHA_INV);
        float k2 = __expf(-c.z * ALPHA_INV);
        float k3 = __expf(-c.w * ALPHA_INV);
        unsigned int w = __builtin_amdgcn_cvt_pk_fp8_f32(k0, k1, 0, false);
        w = __builtin_amdgcn_cvt_pk_fp8_f32(k2, k3, (int)w, true);
        *reinterpret_cast<unsigned int*>(kb + (size_t)r * NN + n0) = w;
        vf2 d0 = __builtin_amdgcn_cvt_pk_f32_fp8(w, false);
        vf2 d1 = __builtin_amdgcn_cvt_pk_f32_fp8(w, true);
        s0 += d0.x; s1 += d0.y; s2 += d1.x; s3 += d1.y;
    }
    float4 ps; ps.x = s0; ps.y = s1; ps.z = s2; ps.w = s3;
    *reinterpret_cast<float4*>(partial + (size_t)(b * MSPLIT + chunk) * NN + n0) = ps;
}

// One Sinkhorn iteration, fully fused:
//   1) re-reduce partials -> v (per block, L2-hot)
//   2) single pass over K chunk: row dots -> u, and u-weighted column partials
// No separate reduce kernel; K read once per iteration; hot loop has no LDS.
__global__ __launch_bounds__(256) void fused_iter(
        const unsigned char* __restrict__ kbuf,
        const float* __restrict__ pin, float* __restrict__ pout,
        float* __restrict__ u, float* __restrict__ vout) {
    __shared__ float smem[4][NN];   // [0] doubles as v staging, then acc scratch
    int b, chunk; decode_bid(blockIdx.x, b, chunk);
    const int t = threadIdx.x, wave = t >> 6, lane = t & 63;

    // --- v-reduce: thread t owns cols 4t..4t+3 ---
    {
        const float* p = pin + (size_t)b * (MSPLIT * NN) + t * 4;
        float s0 = 0.f, s1 = 0.f, s2 = 0.f, s3 = 0.f;
#pragma unroll
        for (int c = 0; c < MSPLIT; ++c) {
            float4 q = *reinterpret_cast<const float4*>(p + (size_t)c * NN);
            s0 += q.x; s1 += q.y; s2 += q.z; s3 += q.w;
        }
        float4 vv;
        vv.x = B_VAL / (s0 + EPSV);
        vv.y = B_VAL / (s1 + EPSV);
        vv.z = B_VAL / (s2 + EPSV);
        vv.w = B_VAL / (s3 + EPSV);
        *reinterpret_cast<float4*>(&smem[0][t * 4]) = vv;
    }
    __syncthreads();

    // --- lane-local v registers: v[16L .. 16L+15] ---
    float vr[16];
#pragma unroll
    for (int q = 0; q < 4; ++q) {
        float4 x = *reinterpret_cast<const float4*>(&smem[0][lane * 16 + q * 4]);
        vr[q * 4 + 0] = x.x; vr[q * 4 + 1] = x.y;
        vr[q * 4 + 2] = x.z; vr[q * 4 + 3] = x.w;
    }
    if (chunk == 0 && wave == 0) {      // persist v (only last iter's matters)
#pragma unroll
        for (int q = 0; q < 4; ++q) {
            float4 w4; w4.x = vr[q*4]; w4.y = vr[q*4+1]; w4.z = vr[q*4+2]; w4.w = vr[q*4+3];
            *reinterpret_cast<float4*>(&vout[(size_t)b * NN + lane * 16 + q * 4]) = w4;
        }
    }

    // --- single pass over this block's 64 rows (16 per wave) ---
    const unsigned char* kb = kbuf + ((size_t)b << 20) + (size_t)(chunk * RPC) * NN;
    float acc[16];
#pragma unroll
    for (int j = 0; j < 16; ++j) acc[j] = 0.f;
    float u_reg = 0.f;

#pragma unroll 4
    for (int i = 0; i < 16; ++i) {
        const int row = wave * 16 + i;
        uint4 kk = *reinterpret_cast<const uint4*>(kb + (size_t)row * NN + lane * 16);
        float k[16]; unpack16(kk, k);
        float dot = 0.f;
#pragma unroll
        for (int j = 0; j < 16; ++j) dot += k[j] * vr[j];
#pragma unroll
        for (int off = 32; off >= 1; off >>= 1)
            dot += __shfl_xor(dot, off, 64);
        const float uu = A_VAL / (dot + EPSV);
        if (lane == i) u_reg = uu;
#pragma unroll
        for (int j = 0; j < 16; ++j) acc[j] += uu * k[j];
    }
    if (lane < 16)
        u[(size_t)b * MM + chunk * RPC + wave * 16 + lane] = u_reg;

    // --- cross-wave reduce of column partials, write pout ---
    __syncthreads();                    // smem[0] (v) is dead for all waves now
#pragma unroll
    for (int q = 0; q < 4; ++q) {
        float4 w4; w4.x = acc[q*4]; w4.y = acc[q*4+1]; w4.z = acc[q*4+2]; w4.w = acc[q*4+3];
        *reinterpret_cast<float4*>(&smem[wave][lane * 16 + q * 4]) = w4;
    }
    __syncthreads();
    {
        float4 s = *reinterpret_cast<const float4*>(&smem[0][t * 4]);
        float4 s1 = *reinterpret_cast<const float4*>(&smem[1][t * 4]);
        float4 s2 = *reinterpret_cast<const float4*>(&smem[2][t * 4]);
        float4 s3 = *reinterpret_cast<const float4*>(&smem[3][t * 4]);
        s.x += s1.x + s2.x + s3.x;
        s.y += s1.y + s2.y + s3.y;
        s.z += s1.z + s2.z + s3.z;
        s.w += s1.w + s2.w + s3.w;
        *reinterpret_cast<float4*>(&pout[(size_t)(b * MSPLIT + chunk) * NN + t * 4]) = s;
    }
}

// Final: P = u * exp(-cost/alpha) * v (exact fp32 K), per-block loss partials.
__global__ __launch_bounds__(256) void finalP(const float* __restrict__ cost,
                                              const float* __restrict__ u,
                                              const float* __restrict__ v,
                                              float* __restrict__ out,
                                              float* __restrict__ lossPart) {
    __shared__ float v_lds[NN];
    __shared__ float u_lds[RPC];
    __shared__ float wsum[4];
    const int blk = blockIdx.x;
    const int b = blk >> 4, chunk = blk & 15;
    const int t = threadIdx.x;

    *reinterpret_cast<float4*>(&v_lds[t * 4]) =
        *reinterpret_cast<const float4*>(v + (size_t)b * NN + t * 4);
    if (t < RPC)
        u_lds[t] = u[(size_t)b * MM + chunk * RPC + t];
    __syncthreads();

    const size_t base = ((size_t)b << 20) + (size_t)(chunk * RPC) * NN;
    const float* cb = cost + base;
    float* pb = out + 1 + base;
    float lacc = 0.f;
    for (int r = 0; r < RPC; ++r) {
        const float uu = u_lds[r];
#pragma unroll
        for (int p = 0; p < 4; ++p) {
            const int col = p * 256 + t;
            const float c = cb[(size_t)r * NN + col];
            const float pval = uu * __expf(-c * ALPHA_INV) * v_lds[col];
            pb[(size_t)r * NN + col] = pval;
            lacc += pval * c;
        }
    }
#pragma unroll
    for (int off = 32; off >= 1; off >>= 1)
        lacc += __shfl_xor(lacc, off, 64);
    if ((t & 63) == 0) wsum[t >> 6] = lacc;
    __syncthreads();
    if (t == 0) lossPart[blk] = wsum[0] + wsum[1] + wsum[2] + wsum[3];
}

__global__ __launch_bounds__(256) void lossReduce(const float* __restrict__ lossPart,
                                                  float* __restrict__ out) {
    __shared__ float wsum[4];
    const int t = threadIdx.x;
    float s = lossPart[t] + lossPart[t + 256] + lossPart[t + 512] + lossPart[t + 768];
#pragma unroll
    for (int off = 32; off >= 1; off >>= 1)
        s += __shfl_xor(s, off, 64);
    if ((t & 63) == 0) wsum[t >> 6] = s;
    __syncthreads();
    if (t == 0) out[0] = (wsum[0] + wsum[1] + wsum[2] + wsum[3]) * (1.0f / (float)BB);
}

extern "C" void kernel_launch(void* const* d_in, const int* in_sizes, int n_in,
                              void* d_out, int out_size, void* d_ws, size_t ws_size,
                              hipStream_t stream) {
    const float* cost = (const float*)d_in[0];
    float* out = (float*)d_out;

    // Scratch carved from the P output region (finalP recomputes exp from cost,
    // reads only u,v — so overwriting these regions last is safe):
    //   kbuf: fp8 K, 64 MB;  ping/pong partials: 4 MB each.
    unsigned char* kbuf = (unsigned char*)d_out + 1024;
    float* ping = (float*)((char*)d_out + 1024 + (size_t)BB * MM * NN);
    float* pong = ping + (size_t)BB * MSPLIT * NN;

    // d_ws: u (256 KB) + v (256 KB) + lossPart (4 KB)
    float* u = (float*)d_ws;
    float* v = u + (size_t)BB * MM;
    float* lossPart = v + (size_t)BB * NN;

    kinit<<<BB * MSPLIT, 256, 0, stream>>>(cost, kbuf, ping);

    float* pcur = ping; float* palt = pong;
    for (int it = 0; it < N_ITERS; ++it) {
        fused_iter<<<BB * MSPLIT, 256, 0, stream>>>(kbuf, pcur, palt, u, v);
        float* tmp = pcur; pcur = palt; palt = tmp;
    }

    finalP<<<BB * MSPLIT, 256, 0, stream>>>(cost, u, v, out, lossPart);
    lossReduce<<<1, 256, 0, stream>>>(lossPart, out);
}